// Round 7
// baseline (69.475 us; speedup 1.0000x reference)
//
#include <hip/hip_runtime.h>
#include <hip/hip_bf16.h>
#include <stdint.h>

typedef __attribute__((ext_vector_type(8))) __bf16 bf16x8;
typedef __attribute__((ext_vector_type(4))) float f32x4;

static constexpr int Bb = 32, Ss = 512, Dd = 1024, Rr = 256;

__device__ __forceinline__ void gload_lds16(const void* g, void* l) {
  __builtin_amdgcn_global_load_lds(
      (const __attribute__((address_space(1))) void*)g,
      (__attribute__((address_space(3))) void*)l, 16, 0, 0);
}

// ---- prep: Bt[512][1024] bf16. rows 0-255 = L^T, rows 256-511 = R ----------
__global__ __launch_bounds__(256) void prep_kernel(
    const float* __restrict__ L, const float* __restrict__ R,
    __bf16* __restrict__ Bt) {
  int i = blockIdx.x * 256 + threadIdx.x;  // 0 .. 512*1024-1 exactly
  int n = i >> 10;
  int d = i & (Dd - 1);
  float v = (n < Rr) ? L[d * Rr + n] : R[(size_t)(n - Rr) * Dd + d];
  Bt[i] = (__bf16)v;
}

// ---- stage 1: C[16384,512] = batch_f32[16384,1024] x Bt[512,1024]^T --------
// BM=64 BN=256 BK=32, 256 thr (4 waves of 64x64), 512 blocks -> 3-4 blk/CU
// (40KB LDS dbuf). Cross-block TLP fills barrier drains (m114). One barrier
// per K-tile, counted vmcnt. A: NONTEMPORAL fp32 reg-stage -> cvt -> swizzled
// ds_write (keeps 1MB B panel L2-resident). B: gload_lds, pre-swizzled src.
__global__ __launch_bounds__(256, 4) void proj_gemm(
    const float* __restrict__ batch,
    const __bf16* __restrict__ Bt,   // [512][1024]
    __bf16* __restrict__ outL,       // [16384][256]
    __bf16* __restrict__ outR) {     // [16384][256]
  // XCD-chunked (bijective, 512 = 8*64): nt-siblings + neighbor mt co-XCD.
  const int s = ((blockIdx.x & 7) << 6) + (blockIdx.x >> 3);
  const int mt = s >> 1;  // 0..255
  const int nt = s & 1;   // 0..1
  const int m0 = mt * 64, n0 = nt * 256;

  __shared__ __align__(16) char smem[40960];
  // A bf16 [64][32]:  buf b at b*4096         (4KB each)
  // B bf16 [256][32]: buf b at 8192 + b*16384 (16KB each)

  const int t = threadIdx.x;
  const int lane = t & 63;
  const int wave = t >> 6;  // 0..3 = N-position (64 cols each)

  f32x4 acc[4][4] = {};
  f32x4 areg0, areg1;

  // A staging: 256 granules (64 rows x 4 of 8 floats), one per thread
  const int arow = t >> 2, ag = t & 3;
  const int ags = ag ^ (arow & 3);

  auto issueA = [&](int k0) {
    const float* src = batch + (size_t)(m0 + arow) * Dd + k0 + ag * 8;
    areg0 = __builtin_nontemporal_load((const f32x4*)src);
    areg1 = __builtin_nontemporal_load((const f32x4*)src + 1);
  };
  auto writeA = [&](int buf) {
    bf16x8 v;
    v[0] = (__bf16)areg0[0]; v[1] = (__bf16)areg0[1];
    v[2] = (__bf16)areg0[2]; v[3] = (__bf16)areg0[3];
    v[4] = (__bf16)areg1[0]; v[5] = (__bf16)areg1[1];
    v[6] = (__bf16)areg1[2]; v[7] = (__bf16)areg1[3];
    *(bf16x8*)(smem + buf * 4096 + (arow * 4 + ags) * 16) = v;
  };
  auto stageB = [&](int buf, int k0) {
    char* Bbuf = smem + 8192 + buf * 16384;
#pragma unroll
    for (int p = 0; p < 4; ++p) {
      int e = p * 256 + t;
      int row = e >> 2, g = e & 3;
      int gs = g ^ (row & 3);  // inverse-swizzled SOURCE, linear LDS dest
      gload_lds16(Bt + (size_t)(n0 + row) * Dd + k0 + gs * 8, Bbuf + e * 16);
    }
  };
  auto compute = [&](int buf) {
    const char* Ab = smem + buf * 4096;
    const char* Bbuf = smem + 8192 + buf * 16384;
    const int g = lane >> 4;  // k-granule 0..3
    bf16x8 a[4], b[4];
#pragma unroll
    for (int m = 0; m < 4; ++m) {
      int row = m * 16 + (lane & 15);
      a[m] = *(const bf16x8*)(Ab + (row * 4 + (g ^ (row & 3))) * 16);
    }
#pragma unroll
    for (int n = 0; n < 4; ++n) {
      int row = wave * 64 + n * 16 + (lane & 15);
      b[n] = *(const bf16x8*)(Bbuf + (row * 4 + (g ^ (row & 3))) * 16);
    }
#pragma unroll
    for (int m = 0; m < 4; ++m)
#pragma unroll
      for (int n = 0; n < 4; ++n)
        acc[m][n] = __builtin_amdgcn_mfma_f32_16x16x32_bf16(a[m], b[n],
                                                            acc[m][n], 0, 0, 0);
  };

  // prologue: tile 0 into buf 0 (A loads issued BEFORE B DMAs -> writeA's
  // compiler-counted vmcnt retires only the A loads)
  issueA(0);
  stageB(0, 0);
  writeA(0);
  asm volatile("s_waitcnt vmcnt(0)" ::: "memory");
  asm volatile("s_waitcnt lgkmcnt(0)" ::: "memory");
  __builtin_amdgcn_s_barrier();

  for (int tt = 0; tt < 32; ++tt) {
    const int buf = tt & 1;
    if (tt < 31) {
      issueA(tt * 32 + 32);           // 2 nt loads, under compute
      stageB(buf ^ 1, tt * 32 + 32);  // 4 gload_lds, under compute
    }
    compute(buf);                     // 8 ds_read_b128 + 16 MFMA
    if (tt < 31) {
      writeA(buf ^ 1);                // counted vmcnt for areg only
      asm volatile("s_waitcnt vmcnt(0)" ::: "memory");   // drain B DMAs
      asm volatile("s_waitcnt lgkmcnt(0)" ::: "memory"); // drain ds_writes
      __builtin_amdgcn_s_barrier();
    }
  }

  // epilogue: nt selects output half; wave covers 64 cols
  __bf16* out = nt ? outR : outL;
  const int col = lane & 15, rgrp = lane >> 4;
#pragma unroll
  for (int m = 0; m < 4; ++m) {
    int r0 = m0 + m * 16 + rgrp * 4;
#pragma unroll
    for (int n = 0; n < 4; ++n) {
      int c = wave * 64 + n * 16 + col;
#pragma unroll
      for (int i = 0; i < 4; ++i)
        out[(size_t)(r0 + i) * Rr + c] = (__bf16)acc[m][n][i];
    }
  }
}

// ---- stage 2: logits[b] = left[b] @ right[b]^T + bias ----------------------
// Per batch: C[512,512] f32 = A[512,256] x Bt[512,256], both bf16 K-contig.
// 64x128 tile, BK=64, single-buffer 24KB, swizzled. 1024 blocks (4/CU).
__global__ __launch_bounds__(256, 4) void score_gemm(
    const __bf16* __restrict__ left,
    const __bf16* __restrict__ right,
    const float* __restrict__ biasp,
    float* __restrict__ out) {
  const int nt = blockIdx.x;  // 0..3
  const int mt = blockIdx.y;  // 0..7
  const int bz = blockIdx.z;  // 0..31
  const __bf16* A = left + (size_t)bz * Ss * Rr;
  const __bf16* B = right + (size_t)bz * Ss * Rr;
  float* O = out + (size_t)bz * Ss * Ss;
  const int m0 = mt * 64, n0 = nt * 128;

  __shared__ __align__(16) char smem[24576];
  // A bf16 [64][64] @ 0 (8KB), B bf16 [128][64] @ 8192 (16KB)

  const int t = threadIdx.x;
  const int lane = t & 63;
  const int wave = t >> 6;
  const int wr = wave >> 1, wc = wave & 1;

  f32x4 acc[2][4] = {};

  for (int it = 0; it < 4; ++it) {
    const int k0 = it * 64;
    __syncthreads();
#pragma unroll
    for (int q = 0; q < 2; ++q) {  // A: 512 granules
      int e = q * 256 + t;
      int row = e >> 3, g = e & 7;
      int gsrc = g ^ (row & 7);
      gload_lds16(A + (size_t)(m0 + row) * Rr + k0 + gsrc * 8, smem + e * 16);
    }
#pragma unroll
    for (int q = 0; q < 4; ++q) {  // B: 1024 granules
      int e = q * 256 + t;
      int row = e >> 3, g = e & 7;
      int gsrc = g ^ (row & 7);
      gload_lds16(B + (size_t)(n0 + row) * Rr + k0 + gsrc * 8,
                  smem + 8192 + e * 16);
    }
    __syncthreads();

#pragma unroll
    for (int kk = 0; kk < 2; ++kk) {
      bf16x8 a[2], b[4];
#pragma unroll
      for (int m = 0; m < 2; ++m) {
        int row = wr * 32 + m * 16 + (lane & 15);
        int g = kk * 4 + (lane >> 4);
        a[m] = *(const bf16x8*)(smem + (row * 8 + (g ^ (row & 7))) * 16);
      }
#pragma unroll
      for (int n = 0; n < 4; ++n) {
        int row = wc * 64 + n * 16 + (lane & 15);
        int g = kk * 4 + (lane >> 4);
        b[n] = *(const bf16x8*)(smem + 8192 +
                                (row * 8 + (g ^ (row & 7))) * 16);
      }
#pragma unroll
      for (int m = 0; m < 2; ++m)
#pragma unroll
        for (int n = 0; n < 4; ++n)
          acc[m][n] = __builtin_amdgcn_mfma_f32_16x16x32_bf16(a[m], b[n],
                                                              acc[m][n], 0, 0, 0);
    }
  }

  const float bias = *biasp;
  const int col = lane & 15, rgrp = lane >> 4;
#pragma unroll
  for (int m = 0; m < 2; ++m) {
    int r0 = m0 + wr * 32 + m * 16 + rgrp * 4;
#pragma unroll
    for (int n = 0; n < 4; ++n) {
      int c = n0 + wc * 64 + n * 16 + col;
#pragma unroll
      for (int i = 0; i < 4; ++i)
        O[(size_t)(r0 + i) * Ss + c] = acc[m][n][i] + bias;
    }
  }
}

extern "C" void kernel_launch(void* const* d_in, const int* in_sizes, int n_in,
                              void* d_out, int out_size, void* d_ws,
                              size_t ws_size, hipStream_t stream) {
  const float* batch = (const float*)d_in[0];  // [32][512][1024]
  const float* projL = (const float*)d_in[1];  // [1024][256]
  const float* projR = (const float*)d_in[2];  // [256][1024]
  const float* bias = (const float*)d_in[3];   // [1]
  float* out = (float*)d_out;                  // [32][512][512]

  char* ws = (char*)d_ws;
  __bf16* left = (__bf16*)(ws);                 // 8,388,608 B [16384][256]
  __bf16* right = (__bf16*)(ws + 8388608);      // 8,388,608 B [16384][256]
  __bf16* Btc = (__bf16*)(ws + 16777216);       // 1,048,576 B [512][1024]

  prep_kernel<<<dim3(2048), dim3(256), 0, stream>>>(projL, projR, Btc);
  proj_gemm<<<dim3(512), dim3(256), 0, stream>>>(batch, Btc, left, right);
  score_gemm<<<dim3(4, 8, 32), dim3(256), 0, stream>>>(left, right, bias, out);
}